// Round 1
// baseline (328.393 us; speedup 1.0000x reference)
//
#include <hip/hip_runtime.h>
#include <stdint.h>

#define LOG2E 1.4426950408889634f

typedef __attribute__((ext_vector_type(8))) short bf16x8;
typedef __attribute__((ext_vector_type(4))) float f32x4;
typedef __attribute__((ext_vector_type(8))) unsigned short u16x8;

#define B_ 2
#define T_ 2048
#define C_ 1024
#define H_ 16
#define D_ 64
#define BT_ 4096
#define N3_ 3072

__device__ __forceinline__ unsigned short f2bf(float f) {
  union { float f; unsigned u; } x; x.f = f;
  return (unsigned short)((x.u + 0x7fffu + ((x.u >> 16) & 1u)) >> 16);
}

// ---------------- prep: fp32 -> bf16 convert ----------------
__global__ void cvt_kernel(const float* __restrict__ in, unsigned short* __restrict__ out, int n) {
  int i = (blockIdx.x * blockDim.x + threadIdx.x) * 4;
  if (i >= n) return;
  float4 v = *(const float4*)(in + i);
  ushort4 o;
  o.x = f2bf(v.x); o.y = f2bf(v.y); o.z = f2bf(v.z); o.w = f2bf(v.w);
  *(ushort4*)(out + i) = o;
}

// ---------------- prep: transpose fp32 [K][N] -> bf16 [N][K] ----------------
__global__ void tr_kernel(const float* __restrict__ in, unsigned short* __restrict__ out, int K, int N) {
  __shared__ unsigned short tile[32][33];
  int n0 = blockIdx.x * 32, k0 = blockIdx.y * 32;
  int tx = threadIdx.x, ty = threadIdx.y;
  tile[ty][tx] = f2bf(in[(size_t)(k0 + ty) * N + n0 + tx]);
  __syncthreads();
  out[(size_t)(n0 + ty) * K + k0 + tx] = tile[tx][ty];
}

// ---------------- GEMM: C[m][n] = sum_k A[m][k] * Bt[n][k], K=1024 ----------------
// 128x128 tile, 256 thr (4 waves, 2x2), each wave 64x64 = 4x4 MFMA 16x16x32 tiles.
// MODE 0: scatter-write q [B,H,T,D], k [B,H,T,D], v [B,H,D,T] as bf16 (N=3072)
// MODE 1: write fp32 out [m][n] (N=1024)
template <int MODE>
__global__ __launch_bounds__(256) void gemm_kernel(
    const unsigned short* __restrict__ A, const unsigned short* __restrict__ Bt,
    unsigned short* __restrict__ qo, unsigned short* __restrict__ ko,
    unsigned short* __restrict__ vo, float* __restrict__ fo) {
  __shared__ unsigned short As[128 * 32];
  __shared__ unsigned short Bs[128 * 32];
  const int tid = threadIdx.x;
  const int wave = tid >> 6, lane = tid & 63;
  const int quad = lane >> 4, l16 = lane & 15;
  const int wm = (wave >> 1) * 64, wn = (wave & 1) * 64;
  const int m0 = blockIdx.y * 128, n0 = blockIdx.x * 128;

  // staging: 512 chunks of 16B per tile; thread t does chunks t and t+256
  const int srow = tid >> 2;        // 0..63
  const int soff = (tid & 3) * 8;   // element offset
  const unsigned short* Ag = A + (size_t)(m0 + srow) * 1024 + soff;
  const unsigned short* Bg = Bt + (size_t)(n0 + srow) * 1024 + soff;
  unsigned short* AsW = As + srow * 32 + soff;
  unsigned short* BsW = Bs + srow * 32 + soff;

  f32x4 acc[4][4] = {};

  for (int k = 0; k < 1024; k += 32) {
    u16x8 a0 = *(const u16x8*)(Ag + k);
    u16x8 a1 = *(const u16x8*)(Ag + 64 * 1024 + k);
    u16x8 b0 = *(const u16x8*)(Bg + k);
    u16x8 b1 = *(const u16x8*)(Bg + 64 * 1024 + k);
    __syncthreads();
    *(u16x8*)AsW = a0;
    *(u16x8*)(AsW + 64 * 32) = a1;
    *(u16x8*)BsW = b0;
    *(u16x8*)(BsW + 64 * 32) = b1;
    __syncthreads();
    bf16x8 af[4], bfr[4];
#pragma unroll
    for (int mi = 0; mi < 4; mi++)
      af[mi] = *(const bf16x8*)(As + (wm + mi * 16 + l16) * 32 + quad * 8);
#pragma unroll
    for (int ni = 0; ni < 4; ni++)
      bfr[ni] = *(const bf16x8*)(Bs + (wn + ni * 16 + l16) * 32 + quad * 8);
#pragma unroll
    for (int mi = 0; mi < 4; mi++)
#pragma unroll
      for (int ni = 0; ni < 4; ni++)
        acc[mi][ni] = __builtin_amdgcn_mfma_f32_16x16x32_bf16(af[mi], bfr[ni], acc[mi][ni], 0, 0, 0);
  }

  // epilogue: C/D layout col=l16, row=quad*4+r (m89/m91-verified)
#pragma unroll
  for (int mi = 0; mi < 4; mi++) {
#pragma unroll
    for (int ni = 0; ni < 4; ni++) {
#pragma unroll
      for (int r = 0; r < 4; r++) {
        int m = m0 + wm + mi * 16 + quad * 4 + r;
        int n = n0 + wn + ni * 16 + l16;
        float val = acc[mi][ni][r];
        if (MODE == 0) {
          int b = m >> 11, t = m & 2047;
          int part = n >> 10, hh = (n >> 6) & 15, d = n & 63;
          unsigned short bv = f2bf(val);
          if (part == 0)
            qo[((size_t)(b * H_ + hh) * T_ + t) * D_ + d] = bv;
          else if (part == 1)
            ko[((size_t)(b * H_ + hh) * T_ + t) * D_ + d] = bv;
          else
            vo[((size_t)(b * H_ + hh) * D_ + d) * T_ + t] = bv;  // V pre-transposed [B,H,D,T]
        } else {
          fo[(size_t)m * 1024 + n] = val;
        }
      }
    }
  }
}

// ---------------- flash attention, causal, D=64 ----------------
// grid: (T/64, B*H). Block: 256 thr = 4 waves; wave w owns q rows [i0+16w, i0+16w+16).
// K/V tiles of 64. q [B,H,T,D], k [B,H,T,D], v [B,H,D,T] bf16; out yb [B,T,H*D] bf16.
__global__ __launch_bounds__(256) void attn_kernel(
    const unsigned short* __restrict__ qb, const unsigned short* __restrict__ kb,
    const unsigned short* __restrict__ vb, unsigned short* __restrict__ yb) {
  const int bh = blockIdx.y;
  const int i0 = blockIdx.x * 64;
  const int tid = threadIdx.x;
  const int wave = tid >> 6, lane = tid & 63;
  const int quad = lane >> 4, l16 = lane & 15;
  const int b = bh >> 4, h = bh & 15;

  __shared__ unsigned short Ks[64 * 64];       // [s][d]
  __shared__ unsigned short Vt[64 * 64];       // [d][s]
  __shared__ unsigned short Ps[4 * 16 * 64];   // per-wave P [q][s]

  const unsigned short* Qg = qb + (size_t)bh * T_ * D_;
  const unsigned short* Kg = kb + (size_t)bh * T_ * D_;
  const unsigned short* Vg = vb + (size_t)bh * D_ * T_;

  // Q fragments held in registers for the whole block (A-layout: m=l16, k=quad*8+j)
  const int qrow = i0 + wave * 16 + l16;
  bf16x8 qf0 = *(const bf16x8*)(Qg + (size_t)qrow * D_ + quad * 8);
  bf16x8 qf1 = *(const bf16x8*)(Qg + (size_t)qrow * D_ + 32 + quad * 8);

  f32x4 o[4] = {};      // o[ni][r] = O[q=quad*4+r][d=ni*16+l16]
  float m_i[4], l_i[4];
#pragma unroll
  for (int r = 0; r < 4; r++) { m_i[r] = -INFINITY; l_i[r] = 0.f; }

  unsigned short* Pw = Ps + wave * 16 * 64;
  const int sr = tid >> 2;         // staging row 0..63
  const int soff = (tid & 3) * 16; // staging col offset

  const int ntiles = (i0 >> 6) + 1;
  for (int jt = 0; jt < ntiles; jt++) {
    const int s0 = jt * 64;
    __syncthreads();
    *(u16x8*)(Ks + sr * 64 + soff) = *(const u16x8*)(Kg + (size_t)(s0 + sr) * 64 + soff);
    *(u16x8*)(Ks + sr * 64 + soff + 8) = *(const u16x8*)(Kg + (size_t)(s0 + sr) * 64 + soff + 8);
    *(u16x8*)(Vt + sr * 64 + soff) = *(const u16x8*)(Vg + (size_t)sr * T_ + s0 + soff);
    *(u16x8*)(Vt + sr * 64 + soff + 8) = *(const u16x8*)(Vg + (size_t)sr * T_ + s0 + soff + 8);
    __syncthreads();

    // S = Q K^T  (S[q][s], C-layout)
    f32x4 s[4];
#pragma unroll
    for (int ni = 0; ni < 4; ni++) {
      bf16x8 kf0 = *(const bf16x8*)(Ks + (ni * 16 + l16) * 64 + quad * 8);
      bf16x8 kf1 = *(const bf16x8*)(Ks + (ni * 16 + l16) * 64 + 32 + quad * 8);
      f32x4 z = {0.f, 0.f, 0.f, 0.f};
      z = __builtin_amdgcn_mfma_f32_16x16x32_bf16(qf0, kf0, z, 0, 0, 0);
      s[ni] = __builtin_amdgcn_mfma_f32_16x16x32_bf16(qf1, kf1, z, 0, 0, 0);
    }

    // online softmax per row (rows distributed: r in 0..3, replicated over 16-lane group)
    const int qr_base = i0 + wave * 16 + quad * 4;
#pragma unroll
    for (int r = 0; r < 4; r++) {
      const int qrow_r = qr_base + r;
      float mx = -INFINITY;
#pragma unroll
      for (int ni = 0; ni < 4; ni++) {
        int scol = s0 + ni * 16 + l16;
        float v = s[ni][r] * 0.125f;
        if (scol > qrow_r) v = -INFINITY;  // causal mask (window clause is vacuous)
        s[ni][r] = v;
        mx = fmaxf(mx, v);
      }
#pragma unroll
      for (int off = 1; off < 16; off <<= 1) mx = fmaxf(mx, __shfl_xor(mx, off, 64));
      float mnew = fmaxf(m_i[r], mx);
      float alpha = exp2f((m_i[r] - mnew) * LOG2E);
      float lsum = 0.f;
#pragma unroll
      for (int ni = 0; ni < 4; ni++) {
        float p = exp2f((s[ni][r] - mnew) * LOG2E);
        s[ni][r] = p;
        lsum += p;
      }
#pragma unroll
      for (int off = 1; off < 16; off <<= 1) lsum += __shfl_xor(lsum, off, 64);
      l_i[r] = l_i[r] * alpha + lsum;
      m_i[r] = mnew;
#pragma unroll
      for (int ni = 0; ni < 4; ni++) o[ni][r] *= alpha;
    }

    // P: C-layout -> A-layout via per-wave LDS round-trip (m120-verified)
#pragma unroll
    for (int r = 0; r < 4; r++)
#pragma unroll
      for (int ni = 0; ni < 4; ni++)
        Pw[(quad * 4 + r) * 64 + ni * 16 + l16] = f2bf(s[ni][r]);

    // O += P V  (B operand from Vt: B[k=s][n=d] contiguous in s)
#pragma unroll
    for (int kk = 0; kk < 2; kk++) {
      bf16x8 pf = *(const bf16x8*)(Pw + l16 * 64 + kk * 32 + quad * 8);
#pragma unroll
      for (int ni = 0; ni < 4; ni++) {
        bf16x8 vf = *(const bf16x8*)(Vt + (ni * 16 + l16) * 64 + kk * 32 + quad * 8);
        o[ni] = __builtin_amdgcn_mfma_f32_16x16x32_bf16(pf, vf, o[ni], 0, 0, 0);
      }
    }
  }

  // epilogue: normalize and write yb [B,T,H*D]
#pragma unroll
  for (int r = 0; r < 4; r++) {
    float inv = 1.0f / l_i[r];
    int t = i0 + wave * 16 + quad * 4 + r;
#pragma unroll
    for (int ni = 0; ni < 4; ni++)
      yb[((size_t)(b * T_ + t)) * 1024 + h * 64 + ni * 16 + l16] = f2bf(o[ni][r] * inv);
  }
}

// ---------------- launch ----------------
extern "C" void kernel_launch(void* const* d_in, const int* in_sizes, int n_in,
                              void* d_out, int out_size, void* d_ws, size_t ws_size,
                              hipStream_t stream) {
  const float* x = (const float*)d_in[0];       // [B,T,C]
  const float* w_qkv = (const float*)d_in[1];   // [C,3C]
  const float* w_proj = (const float*)d_in[2];  // [C,C]
  float* out = (float*)d_out;                   // [B,T,C] fp32

  // workspace layout (bf16 elements); yb aliases xb (dead after GEMM1). ~40 MB total.
  unsigned short* xb = (unsigned short*)d_ws;                 // BT*C      = 4.19M
  unsigned short* wqkvT = xb + (size_t)BT_ * C_;              // 3C*C      = 3.15M
  unsigned short* wprojT = wqkvT + (size_t)N3_ * C_;          // C*C       = 1.05M
  unsigned short* qb = wprojT + (size_t)C_ * C_;              // B*H*T*D   = 4.19M
  unsigned short* kb = qb + (size_t)B_ * H_ * T_ * D_;
  unsigned short* vb = kb + (size_t)B_ * H_ * T_ * D_;
  unsigned short* yb = xb;  // reuse

  cvt_kernel<<<(BT_ * C_ / 4 + 255) / 256, 256, 0, stream>>>(x, xb, BT_ * C_);
  dim3 trb(32, 32);
  tr_kernel<<<dim3(N3_ / 32, C_ / 32), trb, 0, stream>>>(w_qkv, wqkvT, C_, N3_);
  tr_kernel<<<dim3(C_ / 32, C_ / 32), trb, 0, stream>>>(w_proj, wprojT, C_, C_);

  gemm_kernel<0><<<dim3(N3_ / 128, BT_ / 128), 256, 0, stream>>>(xb, wqkvT, qb, kb, vb, nullptr);
  attn_kernel<<<dim3(T_ / 64, B_ * H_), 256, 0, stream>>>(qb, kb, vb, yb);
  gemm_kernel<1><<<dim3(C_ / 128, BT_ / 128), 256, 0, stream>>>(yb, wprojT, nullptr, nullptr, nullptr, out);
}